// Round 1
// baseline (1045.619 us; speedup 1.0000x reference)
//
#include <hip/hip_runtime.h>

#define DD 64
#define NHA 32

using short8 = __attribute__((ext_vector_type(8))) short;
using f32x4  = __attribute__((ext_vector_type(4))) float;
using fvec4  = __attribute__((ext_vector_type(4))) float;

__device__ inline unsigned short f2bf(float x) {
  unsigned int u = __float_as_uint(x);
  unsigned int r = (u + 0x7FFFu + ((u >> 16) & 1u)) >> 16;
  return (unsigned short)r;
}
__device__ inline float bf2f(unsigned short s) {
  return __uint_as_float(((unsigned int)s) << 16);
}
__device__ inline short8 cvt8(fvec4 a, fvec4 b) {
  short8 r;
#pragma unroll
  for (int i = 0; i < 4; ++i) { r[i] = (short)f2bf(a[i]); r[i + 4] = (short)f2bf(b[i]); }
  return r;
}

// B fragments for [64x64] W (row-major, f32 in global): bfr[ks][ct]
// lane holds B[k = ks*32 + (lane>>4)*8 + i][col = ct*16 + (lane&15)]
__device__ inline void load_bfrags(const float* __restrict__ W, short8 bfr[2][4], int lane) {
  int l15 = lane & 15, lh = lane >> 4;
#pragma unroll
  for (int ks = 0; ks < 2; ++ks)
#pragma unroll
    for (int ct = 0; ct < 4; ++ct) {
      short8 v;
#pragma unroll
      for (int i = 0; i < 8; ++i)
        v[i] = (short)f2bf(W[(ks * 32 + lh * 8 + i) * 64 + ct * 16 + l15]);
      bfr[ks][ct] = v;
    }
}

struct ProjArgs {
  const float* W[6];
  unsigned short* out[6];
};

// P = bf16(h @ W)   for 6 different W (grid.y selects)
__global__ __launch_bounds__(256) void proj_kernel(const float* __restrict__ h, ProjArgs pa, int N) {
  int z = blockIdx.y;
  const float* __restrict__ W = pa.W[z];
  unsigned short* __restrict__ out = pa.out[z];
  int lane = threadIdx.x & 63;
  int wv = threadIdx.x >> 6;
  int rowbase = blockIdx.x * 256 + wv * 64;
  int l15 = lane & 15, lh = lane >> 4;

  short8 bfr[2][4];
  load_bfrags(W, bfr, lane);

  f32x4 acc[4][4];
#pragma unroll
  for (int rt = 0; rt < 4; ++rt)
#pragma unroll
    for (int ct = 0; ct < 4; ++ct) acc[rt][ct] = (f32x4){0.f, 0.f, 0.f, 0.f};

#pragma unroll
  for (int rt = 0; rt < 4; ++rt) {
    int row = rowbase + rt * 16 + l15;
    int rc = row < N ? row : 0;
#pragma unroll
    for (int ks = 0; ks < 2; ++ks) {
      const fvec4* p = reinterpret_cast<const fvec4*>(h + (size_t)rc * 64 + ks * 32 + lh * 8);
      short8 a = cvt8(p[0], p[1]);
#pragma unroll
      for (int ct = 0; ct < 4; ++ct)
        acc[rt][ct] = __builtin_amdgcn_mfma_f32_16x16x32_bf16(a, bfr[ks][ct], acc[rt][ct], 0, 0, 0);
    }
  }
#pragma unroll
  for (int rt = 0; rt < 4; ++rt)
#pragma unroll
    for (int rg = 0; rg < 4; ++rg) {
      int row = rowbase + rt * 16 + lh * 4 + rg;
      if (row < N) {
#pragma unroll
        for (int ct = 0; ct < 4; ++ct)
          out[(size_t)row * 64 + ct * 16 + l15] = f2bf(acc[rt][ct][rg]);
      }
    }
}

// per-edge: m = relu(e@We + Psrc[src] + Pdst[dst] + b); atomicAdd into agg[dst]
__global__ __launch_bounds__(256) void edge_kernel(
    const float* __restrict__ e, const int* __restrict__ src, const int* __restrict__ dst,
    const float* __restrict__ W, const float* __restrict__ bmsg,
    const unsigned short* __restrict__ Psrc, const unsigned short* __restrict__ Pdst,
    float* __restrict__ agg, int E) {
  int lane = threadIdx.x & 63;
  int wv = threadIdx.x >> 6;
  int ebase = blockIdx.x * 256 + wv * 64;
  int l15 = lane & 15, lh = lane >> 4;

  short8 bfr[2][4];
  load_bfrags(W, bfr, lane);

  f32x4 acc[4][4];
#pragma unroll
  for (int rt = 0; rt < 4; ++rt)
#pragma unroll
    for (int ct = 0; ct < 4; ++ct) acc[rt][ct] = (f32x4){0.f, 0.f, 0.f, 0.f};

#pragma unroll
  for (int rt = 0; rt < 4; ++rt) {
    int row = ebase + rt * 16 + l15;
    int rc = row < E ? row : 0;
#pragma unroll
    for (int ks = 0; ks < 2; ++ks) {
      const fvec4* p = reinterpret_cast<const fvec4*>(e + (size_t)rc * 64 + ks * 32 + lh * 8);
      short8 a = cvt8(p[0], p[1]);
#pragma unroll
      for (int ct = 0; ct < 4; ++ct)
        acc[rt][ct] = __builtin_amdgcn_mfma_f32_16x16x32_bf16(a, bfr[ks][ct], acc[rt][ct], 0, 0, 0);
    }
  }

  float bv[4];
#pragma unroll
  for (int ct = 0; ct < 4; ++ct) bv[ct] = bmsg[ct * 16 + l15];

#pragma unroll
  for (int rt = 0; rt < 4; ++rt)
#pragma unroll
    for (int rg = 0; rg < 4; ++rg) {
      int eidx = ebase + rt * 16 + lh * 4 + rg;
      if (eidx < E) {
        int s = src[eidx], d = dst[eidx];
        size_t sb = (size_t)s * 64, db = (size_t)d * 64;
#pragma unroll
        for (int ct = 0; ct < 4; ++ct) {
          int c = ct * 16 + l15;
          float v = acc[rt][ct][rg] + bf2f(Psrc[sb + c]) + bf2f(Pdst[db + c]) + bv[ct];
          v = fmaxf(v, 0.0f);
          atomicAdd(&agg[db + c], v);
        }
      }
    }
}

struct NodeArgs {
  const float* agg[2];
  const unsigned short* T[2];
  const float* W[2];
  const float* bn[2];
  unsigned short* U[2];
};

// U = bf16(relu(T + agg@Wagg + b_node))   (grid.y selects graph)
__global__ __launch_bounds__(256) void node_kernel(NodeArgs na, int N) {
  int z = blockIdx.y;
  const float* __restrict__ agg = na.agg[z];
  const unsigned short* __restrict__ T = na.T[z];
  const float* __restrict__ bn = na.bn[z];
  unsigned short* __restrict__ U = na.U[z];
  int lane = threadIdx.x & 63;
  int wv = threadIdx.x >> 6;
  int rowbase = blockIdx.x * 256 + wv * 64;
  int l15 = lane & 15, lh = lane >> 4;

  short8 bfr[2][4];
  load_bfrags(na.W[z], bfr, lane);

  f32x4 acc[4][4];
#pragma unroll
  for (int rt = 0; rt < 4; ++rt)
#pragma unroll
    for (int ct = 0; ct < 4; ++ct) acc[rt][ct] = (f32x4){0.f, 0.f, 0.f, 0.f};

#pragma unroll
  for (int rt = 0; rt < 4; ++rt) {
    int row = rowbase + rt * 16 + l15;
    int rc = row < N ? row : 0;
#pragma unroll
    for (int ks = 0; ks < 2; ++ks) {
      const fvec4* p = reinterpret_cast<const fvec4*>(agg + (size_t)rc * 64 + ks * 32 + lh * 8);
      short8 a = cvt8(p[0], p[1]);
#pragma unroll
      for (int ct = 0; ct < 4; ++ct)
        acc[rt][ct] = __builtin_amdgcn_mfma_f32_16x16x32_bf16(a, bfr[ks][ct], acc[rt][ct], 0, 0, 0);
    }
  }

  float bv[4];
#pragma unroll
  for (int ct = 0; ct < 4; ++ct) bv[ct] = bn[ct * 16 + l15];

#pragma unroll
  for (int rt = 0; rt < 4; ++rt)
#pragma unroll
    for (int rg = 0; rg < 4; ++rg) {
      int row = rowbase + rt * 16 + lh * 4 + rg;
      if (row < N) {
#pragma unroll
        for (int ct = 0; ct < 4; ++ct) {
          int c = ct * 16 + l15;
          float v = acc[rt][ct][rg] + bf2f(T[(size_t)row * 64 + c]) + bv[ct];
          U[(size_t)row * 64 + c] = f2bf(fmaxf(v, 0.0f));
        }
      }
    }
}

// attention over the 2-way stack; 4 threads per node
__global__ __launch_bounds__(256) void attn_kernel(
    const unsigned short* __restrict__ U0, const unsigned short* __restrict__ U1,
    const float* __restrict__ l1w, const float* __restrict__ l1b, const float* __restrict__ l2w,
    float* __restrict__ out, int N) {
  int t = threadIdx.x;
  int node = blockIdx.x * 64 + (t >> 2);
  int q = t & 3;
  if (node >= N) return;
  size_t b0 = (size_t)node * 64;

  float a0[8], a1[8];
#pragma unroll
  for (int i = 0; i < 8; ++i) { a0[i] = l1b[q * 8 + i]; a1[i] = a0[i]; }

  for (int k = 0; k < 64; ++k) {
    float u0 = bf2f(U0[b0 + k]);
    float u1 = bf2f(U1[b0 + k]);
#pragma unroll
    for (int i = 0; i < 8; ++i) {
      float w = l1w[k * 32 + q * 8 + i];
      a0[i] += u0 * w;
      a1[i] += u1 * w;
    }
  }
  float w0 = 0.f, w1 = 0.f;
#pragma unroll
  for (int i = 0; i < 8; ++i) {
    float l2 = l2w[q * 8 + i];
    w0 += tanhf(a0[i]) * l2;
    w1 += tanhf(a1[i]) * l2;
  }
  w0 += __shfl_xor(w0, 1, 4); w0 += __shfl_xor(w0, 2, 4);
  w1 += __shfl_xor(w1, 1, 4); w1 += __shfl_xor(w1, 2, 4);

  float m = fmaxf(w0, w1);
  float e0 = expf(w0 - m), e1 = expf(w1 - m);
  float inv = 1.0f / (e0 + e1);
  float be0 = e0 * inv, be1 = e1 * inv;

#pragma unroll
  for (int j = 0; j < 16; ++j) {
    int c = q * 16 + j;
    out[b0 + c] = be0 * bf2f(U0[b0 + c]) + be1 * bf2f(U1[b0 + c]);
  }
}

extern "C" void kernel_launch(void* const* d_in, const int* in_sizes, int n_in,
                              void* d_out, int out_size, void* d_ws, size_t ws_size,
                              hipStream_t stream) {
  const float* h      = (const float*)d_in[0];
  const float* e_od   = (const float*)d_in[1];
  const float* e_ad   = (const float*)d_in[2];
  const int* src_od   = (const int*)d_in[3];
  const int* dst_od   = (const int*)d_in[4];
  const int* src_ad   = (const int*)d_in[5];
  const int* dst_ad   = (const int*)d_in[6];
  const float* W_src  = (const float*)d_in[7];
  const float* W_dst  = (const float*)d_in[8];
  const float* W_edge = (const float*)d_in[9];
  const float* b_msg  = (const float*)d_in[10];
  const float* W_self = (const float*)d_in[11];
  const float* W_agg  = (const float*)d_in[12];
  const float* b_node = (const float*)d_in[13];
  const float* l1w    = (const float*)d_in[14];
  const float* l1b    = (const float*)d_in[15];
  const float* l2w    = (const float*)d_in[16];
  float* out = (float*)d_out;

  int N = in_sizes[0] / 64;
  int E = in_sizes[1] / 64;

  char* ws = (char*)d_ws;
  size_t NP = (size_t)N * 64 * 2;  // one bf16 [N,64] plane in bytes
  unsigned short* Psrc0 = (unsigned short*)(ws);
  unsigned short* Pdst0 = (unsigned short*)(ws + NP);
  unsigned short* Psrc1 = (unsigned short*)(ws + 2 * NP);
  unsigned short* Pdst1 = (unsigned short*)(ws + 3 * NP);
  unsigned short* T0    = (unsigned short*)(ws + 4 * NP);
  unsigned short* T1    = (unsigned short*)(ws + 5 * NP);
  unsigned short* U0    = (unsigned short*)(ws + 6 * NP);
  unsigned short* U1    = (unsigned short*)(ws + 7 * NP);
  float* agg0 = (float*)(ws + 8 * NP);    // f32 [N,64]
  float* agg1 = (float*)(ws + 10 * NP);   // f32 [N,64]

  // zero both agg buffers (contiguous)
  hipMemsetAsync(agg0, 0, 4 * NP, stream);

  int nb = (N + 255) / 256;
  ProjArgs pa;
  pa.W[0] = W_src;         pa.out[0] = Psrc0;
  pa.W[1] = W_dst;         pa.out[1] = Pdst0;
  pa.W[2] = W_src + 4096;  pa.out[2] = Psrc1;
  pa.W[3] = W_dst + 4096;  pa.out[3] = Pdst1;
  pa.W[4] = W_self;        pa.out[4] = T0;
  pa.W[5] = W_self + 4096; pa.out[5] = T1;
  proj_kernel<<<dim3(nb, 6), 256, 0, stream>>>(h, pa, N);

  int eb = (E + 255) / 256;
  edge_kernel<<<eb, 256, 0, stream>>>(e_od, src_od, dst_od, W_edge, b_msg,
                                      Psrc0, Pdst0, agg0, E);
  edge_kernel<<<eb, 256, 0, stream>>>(e_ad, src_ad, dst_ad, W_edge + 4096, b_msg + 64,
                                      Psrc1, Pdst1, agg1, E);

  NodeArgs na;
  na.agg[0] = agg0; na.T[0] = T0; na.W[0] = W_agg;        na.bn[0] = b_node;      na.U[0] = U0;
  na.agg[1] = agg1; na.T[1] = T1; na.W[1] = W_agg + 4096; na.bn[1] = b_node + 64; na.U[1] = U1;
  node_kernel<<<dim3(nb, 2), 256, 0, stream>>>(na, N);

  attn_kernel<<<(N + 63) / 64, 256, 0, stream>>>(U0, U1, l1w, l1b, l2w, out, N);
}